// Round 3
// baseline (100.995 us; speedup 1.0000x reference)
//
#include <hip/hip_runtime.h>
#include <math.h>

// ---- constants (double-precision folds to float at compile time) ----
static constexpr double D_CUTOFF   = 7.0;
static constexpr double D_SIGMA    = 3.1589;
static constexpr double D_EPS      = 0.1852;
static constexpr double D_GAMMA    = 0.73612;
static constexpr double D_Q        = 1.1128;
static constexpr double D_OH_EQ    = 0.9419;
static constexpr double D_OH_K     = 1059.162;
static constexpr double D_OH_ALPHA = 2.287;
static constexpr double D_ANG_EQ   = 1.87448;
static constexpr double D_ANG_K    = 87.85;
static constexpr double D_SMEAR    = 1.4;
static constexpr double D_PREF     = 332.0637133;

static constexpr double D_SC6   = (D_SIGMA/D_CUTOFF)*(D_SIGMA/D_CUTOFF)*(D_SIGMA/D_CUTOFF)
                                * (D_SIGMA/D_CUTOFF)*(D_SIGMA/D_CUTOFF)*(D_SIGMA/D_CUTOFF);
static constexpr float F_SIG2      = (float)(D_SIGMA*D_SIGMA);
static constexpr float F_4EPS      = (float)(4.0*D_EPS);
static constexpr float F_LJ_SHIFT  = (float)(-4.0*D_EPS*D_SC6*(D_SC6-1.0));
static constexpr float F_Q         = (float)D_Q;
static constexpr float F_QO        = (float)(-D_Q);
static constexpr float F_QH        = (float)(0.5*D_Q);
static constexpr float F_PREF      = (float)D_PREF;
static constexpr float F_INV_S2S   = (float)(1.0/(1.4142135623730951*D_SMEAR));
static constexpr float F_OMG       = (float)((1.0-D_GAMMA)*0.5);
static constexpr float F_OH_EQ     = (float)D_OH_EQ;
static constexpr float F_OH_K      = (float)D_OH_K;
static constexpr float F_OH_ALPHA  = (float)D_OH_ALPHA;
static constexpr float F_ANG_EQ    = (float)D_ANG_EQ;
static constexpr float F_ANG_K     = (float)D_ANG_K;

// ---- fast erfc (A&S 7.1.26, |abs err| <= 1.5e-7) ----
__device__ __forceinline__ float fast_erfc(float x) {
    const float t = __builtin_amdgcn_rcpf(fmaf(0.3275911f, x, 1.0f));
    float p = fmaf(1.061405429f, t, -1.453152027f);
    p = fmaf(p, t, 1.421413741f);
    p = fmaf(p, t, -0.284496736f);
    p = fmaf(p, t, 0.254829592f);
    p *= t;
    return p * __expf(-x * x);
}

// ---- block-wide sum; thread 0 stores to *dst ----
__device__ __forceinline__ void block_reduce_store(float v, float* dst) {
#pragma unroll
    for (int o = 32; o > 0; o >>= 1) v += __shfl_down(v, o, 64);
    __shared__ float smem[16];
    const int lane = threadIdx.x & 63;
    const int w    = threadIdx.x >> 6;
    if (lane == 0) smem[w] = v;
    __syncthreads();
    if (threadIdx.x == 0) {
        const int nw = (blockDim.x + 63) >> 6;
        float t = 0.f;
        for (int k = 0; k < nw; ++k) t += smem[k];
        *dst = t;
    }
}

__device__ __forceinline__ float bond_e(float r) {
    const float dr  = r - F_OH_EQ;
    const float adr = dr * F_OH_ALPHA;
    return 0.5f * F_OH_K * dr * dr * (1.f - adr + adr * adr * (7.f / 12.f));
}

// ---- per-pair energy: screened Coulomb (M-site on the fly) + LJ for O-O ----
// om[mol m] = F_OMG * (dij[m] + dij[n_mol+m]); bond region (~332 KB) is L2-hot.
__device__ __forceinline__ float pair_energy(int i, int j,
        float dx, float dy, float dz, const float* __restrict__ dij, int n_mol) {
    const unsigned ui = (unsigned)i, uj = (unsigned)j;
    const unsigned mi = ui / 3u, mj = uj / 3u;
    const bool iO = (ui == 3u * mi);
    const bool jO = (uj == 3u * mj);
    float sx = dx, sy = dy, sz = dz;
    if (jO) {
        const float* p1 = dij + 3u * (size_t)mj;
        const float* p2 = dij + 3u * (size_t)(n_mol + mj);
        sx += F_OMG * (p1[0] + p2[0]);
        sy += F_OMG * (p1[1] + p2[1]);
        sz += F_OMG * (p1[2] + p2[2]);
    }
    if (iO) {
        const float* p1 = dij + 3u * (size_t)mi;
        const float* p2 = dij + 3u * (size_t)(n_mol + mi);
        sx -= F_OMG * (p1[0] + p2[0]);
        sy -= F_OMG * (p1[1] + p2[1]);
        sz -= F_OMG * (p1[2] + p2[2]);
    }
    const float r2m   = sx*sx + sy*sy + sz*sz;
    const float invrm = __builtin_amdgcn_rsqf(r2m);
    const float rm    = r2m * invrm;
    const float qq    = (iO ? F_QO : F_QH) * (jO ? F_QO : F_QH);
    float e = F_PREF * qq * fast_erfc(rm * F_INV_S2S) * invrm;
    if (iO && jO) {
        const float r2 = dx*dx + dy*dy + dz*dz;
        const float s2 = F_SIG2 * __builtin_amdgcn_rcpf(r2);
        const float c6 = s2 * s2 * s2;
        e += fmaf(F_4EPS, c6 * c6 - c6, F_LJ_SHIFT);
    }
    return e;
}

// ---- fused kernel: 4 pairs/thread (vectorized) + bond/bend/self section ----
// Neighbor-list layout: pair m (m<n_mol) is O->H1 of molecule m; pair n_mol+m
// is O->H2 (bonds are never cut, keep-mask preserves order).
__global__ void __launch_bounds__(256) k_main(
        const int* __restrict__ ni, const int* __restrict__ nj,
        const float* __restrict__ dij, float* __restrict__ partial,
        int n_pairs, int n_mol) {
    const int t = blockIdx.x * blockDim.x + threadIdx.x;
    float e = 0.f;

    // ---- bond/bend/self for molecule t ----
    if (t < n_mol) {
        const float* d1 = dij + 3 * (size_t)t;
        const float* d2 = dij + 3 * (size_t)(n_mol + t);
        const float x1 = d1[0], y1 = d1[1], z1 = d1[2];
        const float x2 = d2[0], y2 = d2[1], z2 = d2[2];
        const float r1 = sqrtf(x1*x1 + y1*y1 + z1*z1);
        const float r2 = sqrtf(x2*x2 + y2*y2 + z2*z2);
        e += bond_e(r1) + bond_e(r2);
        const float ca  = (x1*x2 + y1*y2 + z1*z2) * __builtin_amdgcn_rcpf(r1 * r2);
        const float da  = acosf(ca) - F_ANG_EQ;
        e += 0.5f * F_ANG_K * da * da;
        const float ox = F_OMG * (x1 + x2), oy = F_OMG * (y1 + y2), oz = F_OMG * (z1 + z2);
        const float ax = x1-ox, ay = y1-oy, az = z1-oz;
        const float bx = x2-ox, by = y2-oy, bz = z2-oz;
        const float hx = x1-x2, hy = y1-y2, hz = z1-z2;
        const float inv_mh = __builtin_amdgcn_rsqf(ax*ax+ay*ay+az*az)
                           + __builtin_amdgcn_rsqf(bx*bx+by*by+bz*bz);
        const float inv_hh = __builtin_amdgcn_rsqf(hx*hx+hy*hy+hz*hz);
        e += (inv_mh * F_Q - inv_hh * 0.5f * F_Q) * (0.5f * F_Q * F_PREF);
    }

    // ---- 4-pair chunk ----
    const int p0 = 4 * t;
    if (p0 + 3 < n_pairs) {
        const int4   a  = ((const int4*)ni)[t];
        const int4   b  = ((const int4*)nj)[t];
        const float4 d0 = ((const float4*)dij)[3 * (size_t)t + 0];
        const float4 d1 = ((const float4*)dij)[3 * (size_t)t + 1];
        const float4 d2 = ((const float4*)dij)[3 * (size_t)t + 2];
        e += pair_energy(a.x, b.x, d0.x, d0.y, d0.z, dij, n_mol);
        e += pair_energy(a.y, b.y, d0.w, d1.x, d1.y, dij, n_mol);
        e += pair_energy(a.z, b.z, d1.z, d1.w, d2.x, dij, n_mol);
        e += pair_energy(a.w, b.w, d2.y, d2.z, d2.w, dij, n_mol);
    } else if (p0 < n_pairs) {
        for (int p = p0; p < n_pairs; ++p)
            e += pair_energy(ni[p], nj[p],
                             dij[3 * (size_t)p], dij[3 * (size_t)p + 1],
                             dij[3 * (size_t)p + 2], dij, n_mol);
    }

    block_reduce_store(e, partial + blockIdx.x);
}

// ---- final reduction of block partials -> d_out[0] ----
__global__ void k_reduce(const float* __restrict__ partial, int n, float* __restrict__ out) {
    float v = 0.f;
    for (int i = threadIdx.x; i < n; i += blockDim.x) v += partial[i];
#pragma unroll
    for (int o = 32; o > 0; o >>= 1) v += __shfl_down(v, o, 64);
    __shared__ float smem[16];
    const int lane = threadIdx.x & 63;
    const int w    = threadIdx.x >> 6;
    if (lane == 0) smem[w] = v;
    __syncthreads();
    if (threadIdx.x == 0) {
        const int nw = (blockDim.x + 63) >> 6;
        float t = 0.f;
        for (int k = 0; k < nw; ++k) t += smem[k];
        out[0] = t;
    }
}

extern "C" void kernel_launch(void* const* d_in, const int* in_sizes, int n_in,
                              void* d_out, int out_size, void* d_ws, size_t ws_size,
                              hipStream_t stream) {
    const float* dij = (const float*)d_in[0];
    const int* ni = (const int*)d_in[2];
    const int* nj = (const int*)d_in[3];
    float* out = (float*)d_out;

    const int n_atoms = in_sizes[1];
    const int n_pairs = in_sizes[2];
    const int n_mol   = n_atoms / 3;

    const int B = 256;
    const int n_chunk = (n_pairs + 3) / 4;
    int NB = (n_chunk + B - 1) / B;
    // ensure bond section is fully covered (always true for this problem size)
    const int NB_MOL = (n_mol + B - 1) / B;
    if (NB < NB_MOL) NB = NB_MOL;

    float* partials = (float*)d_ws;

    k_main  <<<NB, B, 0, stream>>>(ni, nj, dij, partials, n_pairs, n_mol);
    k_reduce<<<1,  B, 0, stream>>>(partials, NB, out);
}